// Round 1
// baseline (750.501 us; speedup 1.0000x reference)
//
#include <hip/hip_runtime.h>
#include <math.h>

// ---- problem constants ----
#define BB 8
#define NN 1024
#define HEADC 8
#define SS 256
#define SCH 256
#define SCO 128
#define NE 16
#define INTERC 136
#define C1 256
#define C2 512
#define C3 1024
#define D1 1024
#define D2 2048
#define DOUTC 8192
#define NPTS (BB*NN)      // 8192
#define XCH (HEADC+SS)    // 264
#define TP 32             // points per tile

// ---- workspace layout (floats) ----  total ~18.9 MB
#define OFF_XT    ((size_t)0)           // [B*N][264]   2162688
#define OFF_ROUT  ((size_t)2162688)     // [B*N][128]   1048576
#define OFF_WT1   ((size_t)3211264)     // [136][256]   34816
#define OFF_WT2   ((size_t)3246080)     // [256][512]   131072
#define OFF_WT3   ((size_t)3377152)     // [512][1024]  524288
#define OFF_PMAX  ((size_t)3901440)     // [256][1024]  262144
#define OFF_LAT   ((size_t)4163584)     // [8][1024]    8192
#define OFF_D1    ((size_t)4171776)     // [8][1024]    8192
#define OFF_D2    ((size_t)4179968)     // [8][2048]    16384
#define OFF_DPART ((size_t)4196352)     // up to 524288
#define OFF_IDX   ((size_t)4720640)     // int[8192]
#define OFF_OFFS  ((size_t)4728832)     // int[17]

// ---------------------------------------------------------------------------
// Tiled transpose: src [bat][R][C] -> dst [bat][C][R]
// ---------------------------------------------------------------------------
__global__ __launch_bounds__(256) void k_transpose(
    const float* __restrict__ src, float* __restrict__ dst,
    int R, int C, size_t srcBS, size_t dstBS) {
  __shared__ float t[32][33];
  const float* s = src + (size_t)blockIdx.z * srcBS;
  float* d = dst + (size_t)blockIdx.z * dstBS;
  int r0 = blockIdx.y * 32, c0 = blockIdx.x * 32;
  int tx = threadIdx.x & 31, ty = threadIdx.x >> 5;   // ty 0..7
  for (int yy = ty; yy < 32; yy += 8) {
    int r = r0 + yy, c = c0 + tx;
    if (r < R && c < C) t[yy][tx] = s[(size_t)r * C + c];
  }
  __syncthreads();
  for (int yy = ty; yy < 32; yy += 8) {
    int c = c0 + yy, r = r0 + tx;
    if (r < R && c < C) d[(size_t)c * R + r] = t[tx][yy];
  }
}

// ---------------------------------------------------------------------------
// Bucket points by category (single block, 1024 threads)
// ---------------------------------------------------------------------------
__global__ __launch_bounds__(1024) void k_bucket(
    const int* __restrict__ cats, int* __restrict__ idx, int* __restrict__ offs) {
  __shared__ int cnt[NE];
  __shared__ int base[NE + 1];
  __shared__ int cur[NE];
  int tid = threadIdx.x;
  if (tid < NE) cnt[tid] = 0;
  __syncthreads();
  for (int p = tid; p < NPTS; p += 1024) atomicAdd(&cnt[cats[p]], 1);
  __syncthreads();
  if (tid == 0) {
    int s = 0;
    for (int e = 0; e < NE; ++e) { base[e] = s; cur[e] = s; s += cnt[e]; }
    base[NE] = s;
  }
  __syncthreads();
  for (int p = tid; p < NPTS; p += 1024) {
    int e = cats[p];
    int pos = atomicAdd(&cur[e], 1);
    idx[pos] = p;
  }
  if (tid <= NE) offs[tid] = base[tid];
}

// ---------------------------------------------------------------------------
// Expert-routed shape MLP: sf[256] -> relu(W1)+b1 -> [256] -> W2+b2 -> [128]
// One block = 32 points of one expert. 256 threads.
// ---------------------------------------------------------------------------
__global__ __launch_bounds__(256) void k_route(
    const float* __restrict__ xT, const int* __restrict__ idx,
    const int* __restrict__ offs,
    const float* __restrict__ W1, const float* __restrict__ b1,
    const float* __restrict__ W2, const float* __restrict__ b2,
    float* __restrict__ routedT) {
  __shared__ float sf[TP][SS];   // 32 KB
  __shared__ float h[TP][SCH];   // 32 KB
  __shared__ int pts[TP];
  int e = blockIdx.x >> 8;       // MAX_T = 256 tiles/expert
  int t = blockIdx.x & 255;
  int s0 = offs[e];
  int cnt = offs[e + 1] - s0;
  int p0 = t * TP;
  if (p0 >= cnt) return;
  int nr = min(TP, cnt - p0);
  int tid = threadIdx.x;
  if (tid < TP) pts[tid] = (tid < nr) ? idx[s0 + p0 + tid] : -1;
  __syncthreads();
  for (int k = tid; k < TP * SS; k += 256) {
    int r = k >> 8, c = k & 255;
    int p = pts[r];
    sf[r][c] = (p >= 0) ? xT[(size_t)p * XCH + HEADC + c] : 0.f;
  }
  __syncthreads();
  // ---- layer 1: column j = tid ----
  {
    int j = tid;
    float acc[TP];
#pragma unroll
    for (int r = 0; r < TP; ++r) acc[r] = 0.f;
    const float* w1 = W1 + (size_t)e * SS * SCH + j;
    for (int i4 = 0; i4 < SS / 4; ++i4) {
      float w0 = w1[(size_t)(4 * i4 + 0) * SCH];
      float wv1 = w1[(size_t)(4 * i4 + 1) * SCH];
      float wv2 = w1[(size_t)(4 * i4 + 2) * SCH];
      float wv3 = w1[(size_t)(4 * i4 + 3) * SCH];
#pragma unroll
      for (int r = 0; r < TP; ++r) {
        float4 sv = ((const float4*)sf[r])[i4];
        acc[r] += sv.x * w0 + sv.y * wv1 + sv.z * wv2 + sv.w * wv3;
      }
    }
    float bv = b1[e * SCH + j];
#pragma unroll
    for (int r = 0; r < TP; ++r) h[r][j] = fmaxf(acc[r] + bv, 0.f);
  }
  __syncthreads();
  // ---- layer 2: j = tid&127, 16 rows per thread ----
  {
    int j = tid & 127;
    int r0 = (tid >> 7) * 16;
    float acc[16];
#pragma unroll
    for (int r = 0; r < 16; ++r) acc[r] = 0.f;
    const float* w2 = W2 + (size_t)e * SCH * SCO + j;
    for (int i4 = 0; i4 < SCH / 4; ++i4) {
      float w0 = w2[(size_t)(4 * i4 + 0) * SCO];
      float wv1 = w2[(size_t)(4 * i4 + 1) * SCO];
      float wv2 = w2[(size_t)(4 * i4 + 2) * SCO];
      float wv3 = w2[(size_t)(4 * i4 + 3) * SCO];
#pragma unroll
      for (int rr = 0; rr < 16; ++rr) {
        float4 hv = ((const float4*)h[r0 + rr])[i4];
        acc[rr] += hv.x * w0 + hv.y * wv1 + hv.z * wv2 + hv.w * wv3;
      }
    }
    float bv = b2[e * SCO + j];
    for (int rr = 0; rr < 16; ++rr) {
      int r = r0 + rr;
      if (r < nr) routedT[(size_t)pts[r] * SCO + j] = acc[rr] + bv;
    }
  }
}

// ---------------------------------------------------------------------------
// Conv stack 136->256->512->1024 + per-tile max. One block = 32 points.
// LDS: 17.4 + 32 + 64 = ~113 KB -> 1 block/CU, 256 blocks.
// ---------------------------------------------------------------------------
__global__ __launch_bounds__(256) void k_conv(
    const float* __restrict__ xT, const float* __restrict__ routedT,
    const float* __restrict__ WcT1, const float* __restrict__ bc1,
    const float* __restrict__ WcT2, const float* __restrict__ bc2,
    const float* __restrict__ WcT3, const float* __restrict__ bc3,
    float* __restrict__ pmax) {
  __shared__ float xi[TP][INTERC];
  __shared__ float h1[TP][C1];
  __shared__ float h2[TP][C2];
  int p0 = blockIdx.x * TP;
  int tid = threadIdx.x;
  {
    int r = tid >> 3;
    for (int c = tid & 7; c < INTERC; c += 8) {
      float v;
      if (c < HEADC) v = xT[(size_t)(p0 + r) * XCH + c];
      else v = routedT[(size_t)(p0 + r) * SCO + (c - HEADC)];
      xi[r][c] = v;
    }
  }
  __syncthreads();
  // ---- L1: 136 -> 256, 1 col/thread ----
  {
    int j = tid;
    float acc[TP];
#pragma unroll
    for (int r = 0; r < TP; ++r) acc[r] = 0.f;
    for (int i4 = 0; i4 < INTERC / 4; ++i4) {
      const float* w = WcT1 + (size_t)(4 * i4) * C1 + j;
      float w0 = w[0], wv1 = w[C1], wv2 = w[2 * C1], wv3 = w[3 * C1];
#pragma unroll
      for (int r = 0; r < TP; ++r) {
        float4 v = ((const float4*)xi[r])[i4];
        acc[r] += v.x * w0 + v.y * wv1 + v.z * wv2 + v.w * wv3;
      }
    }
    float bv = bc1[j];
#pragma unroll
    for (int r = 0; r < TP; ++r) h1[r][j] = fmaxf(acc[r] + bv, 0.f);
  }
  __syncthreads();
  // ---- L2: 256 -> 512, 2 cols/thread ----
  {
    int j0 = tid, j1 = tid + 256;
    float acc0[TP], acc1[TP];
#pragma unroll
    for (int r = 0; r < TP; ++r) { acc0[r] = 0.f; acc1[r] = 0.f; }
    for (int i4 = 0; i4 < C1 / 4; ++i4) {
      const float* w = WcT2 + (size_t)(4 * i4) * C2;
      float w00 = w[j0], w01 = w[j1];
      float w10 = w[C2 + j0], w11 = w[C2 + j1];
      float w20 = w[2 * C2 + j0], w21 = w[2 * C2 + j1];
      float w30 = w[3 * C2 + j0], w31 = w[3 * C2 + j1];
#pragma unroll
      for (int r = 0; r < TP; ++r) {
        float4 v = ((const float4*)h1[r])[i4];
        acc0[r] += v.x * w00 + v.y * w10 + v.z * w20 + v.w * w30;
        acc1[r] += v.x * w01 + v.y * w11 + v.z * w21 + v.w * w31;
      }
    }
    float b0 = bc2[j0], b1v = bc2[j1];
#pragma unroll
    for (int r = 0; r < TP; ++r) {
      h2[r][j0] = fmaxf(acc0[r] + b0, 0.f);
      h2[r][j1] = fmaxf(acc1[r] + b1v, 0.f);
    }
  }
  __syncthreads();
  // ---- L3: 512 -> 1024 + max over rows, 2 cols/thread x 2 passes ----
  for (int half = 0; half < 2; ++half) {
    int j0 = half * 512 + tid;
    int j1 = j0 + 256;
    float acc0[TP], acc1[TP];
#pragma unroll
    for (int r = 0; r < TP; ++r) { acc0[r] = 0.f; acc1[r] = 0.f; }
    for (int i4 = 0; i4 < C2 / 4; ++i4) {
      const float* w = WcT3 + (size_t)(4 * i4) * C3;
      float w00 = w[j0], w01 = w[j1];
      float w10 = w[C3 + j0], w11 = w[C3 + j1];
      float w20 = w[2 * C3 + j0], w21 = w[2 * C3 + j1];
      float w30 = w[3 * C3 + j0], w31 = w[3 * C3 + j1];
#pragma unroll
      for (int r = 0; r < TP; ++r) {
        float4 v = ((const float4*)h2[r])[i4];
        acc0[r] += v.x * w00 + v.y * w10 + v.z * w20 + v.w * w30;
        acc1[r] += v.x * w01 + v.y * w11 + v.z * w21 + v.w * w31;
      }
    }
    float m0 = -INFINITY, m1 = -INFINITY;
#pragma unroll
    for (int r = 0; r < TP; ++r) { m0 = fmaxf(m0, acc0[r]); m1 = fmaxf(m1, acc1[r]); }
    pmax[(size_t)blockIdx.x * C3 + j0] = m0 + bc3[j0];
    pmax[(size_t)blockIdx.x * C3 + j1] = m1 + bc3[j1];
  }
}

// ---------------------------------------------------------------------------
// latent = max over the 32 tiles of each batch; write to ws + d_out tail
// ---------------------------------------------------------------------------
__global__ __launch_bounds__(256) void k_latmax(
    const float* __restrict__ pmax, float* __restrict__ lat,
    float* __restrict__ outLat) {
  int id = blockIdx.x * 256 + threadIdx.x;   // 0..8191
  int b = id >> 10, o = id & 1023;
  float m = -INFINITY;
  for (int t = 0; t < 32; ++t)
    m = fmaxf(m, pmax[((size_t)(b * 32 + t) << 10) + o]);
  lat[id] = m;
  outLat[id] = m;
}

// ---------------------------------------------------------------------------
// Decoder partial GEMM: A[8][K] @ W[K][Ncol] k-split into gridDim.y chunks
// ---------------------------------------------------------------------------
__global__ __launch_bounds__(256) void k_gemm_part(
    const float* __restrict__ A, const float* __restrict__ W,
    float* __restrict__ part, int K, int Ncol, int chunkLog) {
  __shared__ float a[8][256];
  int chunk = 1 << chunkLog;
  int i0 = blockIdx.y << chunkLog;
  int j = blockIdx.x * 256 + threadIdx.x;
  for (int k = threadIdx.x; k < 8 * chunk; k += 256) {
    int r = k >> chunkLog, i = k & (chunk - 1);
    a[r][i] = A[(size_t)r * K + i0 + i];
  }
  __syncthreads();
  float acc[8];
#pragma unroll
  for (int r = 0; r < 8; ++r) acc[r] = 0.f;
  const float* wp = W + (size_t)i0 * Ncol + j;
  for (int i4 = 0; i4 < (chunk >> 2); ++i4) {
    float w0 = wp[(size_t)(4 * i4 + 0) * Ncol];
    float w1 = wp[(size_t)(4 * i4 + 1) * Ncol];
    float w2 = wp[(size_t)(4 * i4 + 2) * Ncol];
    float w3 = wp[(size_t)(4 * i4 + 3) * Ncol];
#pragma unroll
    for (int r = 0; r < 8; ++r) {
      float4 av = ((const float4*)a[r])[i4];
      acc[r] += av.x * w0 + av.y * w1 + av.z * w2 + av.w * w3;
    }
  }
#pragma unroll
  for (int r = 0; r < 8; ++r)
    part[((size_t)(blockIdx.y * 8 + r)) * Ncol + j] = acc[r];
}

__global__ __launch_bounds__(256) void k_reduce(
    const float* __restrict__ part, const float* __restrict__ bias,
    float* __restrict__ out, int ncolLog, int KC, int doRelu) {
  int o = blockIdx.x * 256 + threadIdx.x;     // o = r*Ncol + j
  int j = o & ((1 << ncolLog) - 1);
  float s = bias[j];
  for (int kc = 0; kc < KC; ++kc)
    s += part[((size_t)kc << (ncolLog + 3)) + o];
  if (doRelu) s = fmaxf(s, 0.f);
  out[o] = s;
}

// ---------------------------------------------------------------------------
extern "C" void kernel_launch(void* const* d_in, const int* in_sizes, int n_in,
                              void* d_out, int out_size, void* d_ws, size_t ws_size,
                              hipStream_t stream) {
  const float* x    = (const float*)d_in[0];
  const int*   cats = (const int*)d_in[1];
  const float* W1   = (const float*)d_in[2];
  const float* b1   = (const float*)d_in[3];
  const float* W2   = (const float*)d_in[4];
  const float* b2   = (const float*)d_in[5];
  const float* Wc1  = (const float*)d_in[6];
  const float* bc1  = (const float*)d_in[7];
  const float* Wc2  = (const float*)d_in[8];
  const float* bc2  = (const float*)d_in[9];
  const float* Wc3  = (const float*)d_in[10];
  const float* bc3  = (const float*)d_in[11];
  const float* Wd1  = (const float*)d_in[12];
  const float* bd1  = (const float*)d_in[13];
  const float* Wd2  = (const float*)d_in[14];
  const float* bd2  = (const float*)d_in[15];
  const float* Wd3  = (const float*)d_in[16];
  const float* bd3  = (const float*)d_in[17];
  float* out = (float*)d_out;                 // [8*1024*8] out  then [8*1024] latent

  float* ws = (float*)d_ws;
  float* xT      = ws + OFF_XT;
  float* routedT = ws + OFF_ROUT;
  float* WT1     = ws + OFF_WT1;
  float* WT2     = ws + OFF_WT2;
  float* WT3     = ws + OFF_WT3;
  float* pmax    = ws + OFF_PMAX;
  float* lat     = ws + OFF_LAT;
  float* d1w     = ws + OFF_D1;
  float* d2w     = ws + OFF_D2;
  float* dpart   = ws + OFF_DPART;
  int*   idx     = (int*)(ws + OFF_IDX);
  int*   offs    = (int*)(ws + OFF_OFFS);

  // transposes: x -> point-major, Wc* -> [in][out]
  k_transpose<<<dim3(32, 9, BB), 256, 0, stream>>>(x, xT, XCH, NN,
                                                   (size_t)XCH * NN, (size_t)XCH * NN);
  k_transpose<<<dim3(5, 8, 1), 256, 0, stream>>>(Wc1, WT1, C1, INTERC, 0, 0);
  k_transpose<<<dim3(8, 16, 1), 256, 0, stream>>>(Wc2, WT2, C2, C1, 0, 0);
  k_transpose<<<dim3(16, 32, 1), 256, 0, stream>>>(Wc3, WT3, C3, C2, 0, 0);

  // routing
  k_bucket<<<1, 1024, 0, stream>>>(cats, idx, offs);
  k_route<<<NE * 256, 256, 0, stream>>>(xT, idx, offs, W1, b1, W2, b2, routedT);

  // conv stack + pooling
  k_conv<<<NPTS / TP, 256, 0, stream>>>(xT, routedT, WT1, bc1, WT2, bc2, WT3, bc3, pmax);
  k_latmax<<<32, 256, 0, stream>>>(pmax, lat, out + 65536);

  // decoder
  k_gemm_part<<<dim3(4, 32), 256, 0, stream>>>(lat, Wd1, dpart, 1024, 1024, 5);
  k_reduce<<<32, 256, 0, stream>>>(dpart, bd1, d1w, 10, 32, 1);
  k_gemm_part<<<dim3(8, 16), 256, 0, stream>>>(d1w, Wd2, dpart, 1024, 2048, 6);
  k_reduce<<<64, 256, 0, stream>>>(dpart, bd2, d2w, 11, 16, 1);
  k_gemm_part<<<dim3(32, 8), 256, 0, stream>>>(d2w, Wd3, dpart, 2048, 8192, 8);
  k_reduce<<<256, 256, 0, stream>>>(dpart, bd3, out, 13, 8, 0);
  (void)in_sizes; (void)n_in; (void)out_size; (void)ws_size;
}

// Round 2
// 311.588 us; speedup vs baseline: 2.4086x; 2.4086x over previous
//
#include <hip/hip_runtime.h>
#include <math.h>

// ---- problem constants ----
#define BB 8
#define NN 1024
#define HEADC 8
#define SS 256
#define SCO 128
#define NE 16
#define C1 256
#define C2 512
#define C3 1024
#define NPTS (BB*NN)      // 8192
#define XCH (HEADC+SS)    // 264
#define K1P 192           // conv L1 K padded (136 -> 192)
#define BK 64

typedef unsigned short ushortT;
typedef __attribute__((ext_vector_type(8))) short bf16x8;   // 8 bf16 = 4 VGPRs
typedef __attribute__((ext_vector_type(4))) float f32x4;

// ---- workspace layout (byte offsets, all 256-aligned) ----
// h2 [8192][512]bf16 aliases XTB+HB (both dead by conv L2)
#define OB_XTB   0ull          // ushort [8192][264]
#define OB_HB    4325376ull    // ushort [8192][256]  (bucket-ordered hidden)
#define OB_H2    0ull          // ushort [8192][512]
#define OB_XI    8519680ull    // ushort [8192][192]  (head 8 | routed 128 | pad 56)
#define OB_H1    11665408ull   // ushort [8192][256]
#define OB_WT1   15859712ull   // ushort [256][192]
#define OB_WT2   15958016ull   // ushort [512][256]
#define OB_WT3   16220160ull   // ushort [1024][512]
#define OB_W1T   17268736ull   // ushort [16][256][256]
#define OB_W2T   19365888ull   // ushort [16][128][256]
#define OB_PMAX  20414464ull   // float [64][1024]
#define OB_LAT   20676608ull   // float [8][1024]
#define OB_D1    20709376ull   // float [8][1024]
#define OB_D2    20742144ull   // float [8][2048]
#define OB_DPART 20807680ull   // float up to 524288
#define OB_IDX   22904832ull   // int [8192]
#define OB_OFFS  22937600ull   // int [17]

__device__ __forceinline__ ushortT f2b(float f) {
  unsigned u = __float_as_uint(f);
  return (ushortT)((u + 0x7FFFu + ((u >> 16) & 1u)) >> 16);
}

// ---------------------------------------------------------------------------
// x [B][264][1024] f32  ->  xTb [B*N][264] bf16 ; head cols into xi
// ---------------------------------------------------------------------------
__global__ __launch_bounds__(256) void k_prep_x(
    const float* __restrict__ x, ushortT* __restrict__ xTb, ushortT* __restrict__ xi) {
  __shared__ float t[32][33];
  int b = blockIdx.z;
  int n0 = blockIdx.x * 32, c0 = blockIdx.y * 32;
  int tx = threadIdx.x & 31, ty = threadIdx.x >> 5;
  const float* s = x + (size_t)b * XCH * NN;
  for (int yy = ty; yy < 32; yy += 8) {
    int c = c0 + yy;
    if (c < XCH) t[yy][tx] = s[(size_t)c * NN + n0 + tx];
  }
  __syncthreads();
  for (int yy = ty; yy < 32; yy += 8) {
    int n = n0 + yy, c = c0 + tx;
    if (c < XCH) {
      ushortT v = f2b(t[tx][yy]);
      xTb[(size_t)(b * NN + n) * XCH + c] = v;
      if (c < HEADC) xi[(size_t)(b * NN + n) * K1P + c] = v;
    }
  }
}

// zero xi pad cols [136,192)
__global__ __launch_bounds__(256) void k_zero_xi(ushortT* __restrict__ xi) {
  int i = blockIdx.x * 256 + threadIdx.x;
  if (i >= NPTS * 56) return;
  int p = i / 56, c = 136 + i % 56;
  xi[(size_t)p * K1P + c] = 0;
}

// f32 [rows][cs] -> bf16 [rows][cd] with zero pad cols >= cs
__global__ __launch_bounds__(256) void k_cvt_pad(
    const float* __restrict__ src, ushortT* __restrict__ dst, int cs, int cd, int total) {
  int i = blockIdx.x * 256 + threadIdx.x;
  if (i >= total) return;
  int r = i / cd, c = i % cd;
  dst[i] = (c < cs) ? f2b(src[(size_t)r * cs + c]) : (ushortT)0;
}

// batched transpose f32 [z][R][C] -> bf16 [z][C][R]
__global__ __launch_bounds__(256) void k_transpose_wb(
    const float* __restrict__ src, ushortT* __restrict__ dst, int R, int C,
    size_t sBS, size_t dBS) {
  __shared__ float t[32][33];
  const float* s = src + (size_t)blockIdx.z * sBS;
  ushortT* d = dst + (size_t)blockIdx.z * dBS;
  int r0 = blockIdx.y * 32, c0 = blockIdx.x * 32;
  int tx = threadIdx.x & 31, ty = threadIdx.x >> 5;
  for (int yy = ty; yy < 32; yy += 8) {
    int r = r0 + yy, c = c0 + tx;
    if (r < R && c < C) t[yy][tx] = s[(size_t)r * C + c];
  }
  __syncthreads();
  for (int yy = ty; yy < 32; yy += 8) {
    int c = c0 + yy, r = r0 + tx;
    if (r < R && c < C) d[(size_t)c * R + r] = f2b(t[tx][yy]);
  }
}

// ---------------------------------------------------------------------------
// Bucket points by category (single block)
// ---------------------------------------------------------------------------
__global__ __launch_bounds__(1024) void k_bucket(
    const int* __restrict__ cats, int* __restrict__ idx, int* __restrict__ offs) {
  __shared__ int cnt[NE];
  __shared__ int base[NE + 1];
  __shared__ int cur[NE];
  int tid = threadIdx.x;
  if (tid < NE) cnt[tid] = 0;
  __syncthreads();
  for (int p = tid; p < NPTS; p += 1024) atomicAdd(&cnt[cats[p]], 1);
  __syncthreads();
  if (tid == 0) {
    int s = 0;
    for (int e = 0; e < NE; ++e) { base[e] = s; cur[e] = s; s += cnt[e]; }
    base[NE] = s;
  }
  __syncthreads();
  for (int p = tid; p < NPTS; p += 1024) {
    int pos = atomicAdd(&cur[cats[p]], 1);
    idx[pos] = p;
  }
  if (tid <= NE) offs[tid] = base[tid];
}

// ---------------------------------------------------------------------------
// Generic bf16 MFMA GEMM, 128x128 tile, 4 waves (2x2 of 64x64), BK=64.
// A [*, lda] bf16 row-major; Bt [N][ldb] bf16 (= B transposed, weight [out][in]).
// XOR swizzle: 16B chunk slot ^= (row&7)  -> conflict-free ds_write/ds_read_b128.
// MODE 0: C_bf16[m0+row][ldc] = maybe_relu(acc + bias[col])          (conv L1/L2)
// MODE 1: pmax[blockIdx.y][n0+col]  = colmax(acc) + bias[col]        (conv L3)
// MODE 2: gather A rows via idx (xTb, col off +8); C rows bucket-linear (route L1)
// MODE 3: A rows bucket-linear; scatter C rows via idx, col off +8    (route L2)
// ---------------------------------------------------------------------------
template<int MODE>
__global__ __launch_bounds__(256) void k_gemm(
    const ushortT* __restrict__ A, int lda,
    const ushortT* __restrict__ Bt, int ldb,
    const float* __restrict__ bias,
    ushortT* __restrict__ Cb, int ldc,
    float* __restrict__ pmaxOut,
    const int* __restrict__ idx, const int* __restrict__ offsp,
    int K, int relu) {
  __shared__ ushortT As[128 * BK];
  __shared__ ushortT Bs[128 * BK];
  __shared__ int pts[128];
  __shared__ float smax[2][128];
  int tid = threadIdx.x;
  int wave = tid >> 6, lane = tid & 63;
  int wm = wave >> 1, wn = wave & 1;
  int g = lane >> 4, lr = lane & 15;
  int n0 = blockIdx.x * 128;
  int m0 = 0, nr = 128, bucket0 = 0;

  if constexpr (MODE == 2 || MODE == 3) {
    int e = blockIdx.y, t = blockIdx.z;
    int s0 = offsp[e];
    int cnt = offsp[e + 1] - s0;
    int p0 = t * 128;
    if (p0 >= cnt) return;
    nr = min(128, cnt - p0);
    bucket0 = s0 + p0;
    Bt += (size_t)e * ((MODE == 2) ? 256 * 256 : 128 * 256);
    bias += e * ((MODE == 2) ? 256 : 128);
    if (tid < 128) pts[tid] = (tid < nr) ? idx[bucket0 + tid] : 0;
  } else {
    m0 = blockIdx.y * 128;
  }

  f32x4 acc[4][4];
#pragma unroll
  for (int mi = 0; mi < 4; ++mi)
#pragma unroll
    for (int nj = 0; nj < 4; ++nj) acc[mi][nj] = (f32x4)(0.f);

  int nkt = K / BK;
  for (int kt = 0; kt < nkt; ++kt) {
    int k0 = kt * BK;
    __syncthreads();   // LDS reuse guard (covers pts staging on kt==0)
#pragma unroll
    for (int i = 0; i < 4; ++i) {
      int c = tid + i * 256;
      int row = c >> 3, slot = c & 7;
      int ss = slot ^ (row & 7);
      uint4 v;
      if constexpr (MODE == 2) {
        if (row < nr) v = *(const uint4*)(A + (size_t)pts[row] * lda + 8 + k0 + slot * 8);
        else { v.x = v.y = v.z = v.w = 0u; }
      } else if constexpr (MODE == 3) {
        if (row < nr) v = *(const uint4*)(A + (size_t)(bucket0 + row) * lda + k0 + slot * 8);
        else { v.x = v.y = v.z = v.w = 0u; }
      } else {
        v = *(const uint4*)(A + (size_t)(m0 + row) * lda + k0 + slot * 8);
      }
      *(uint4*)(As + row * BK + ss * 8) = v;
      uint4 w = *(const uint4*)(Bt + (size_t)(n0 + row) * ldb + k0 + slot * 8);
      *(uint4*)(Bs + row * BK + ss * 8) = w;
    }
    __syncthreads();
#pragma unroll
    for (int kk = 0; kk < 2; ++kk) {
      bf16x8 av[4], bv[4];
#pragma unroll
      for (int mi = 0; mi < 4; ++mi) {
        int row = wm * 64 + mi * 16 + lr;
        int slot = (kk * 4 + g) ^ (row & 7);
        av[mi] = *(const bf16x8*)(As + row * BK + slot * 8);
      }
#pragma unroll
      for (int nj = 0; nj < 4; ++nj) {
        int row = wn * 64 + nj * 16 + lr;
        int slot = (kk * 4 + g) ^ (row & 7);
        bv[nj] = *(const bf16x8*)(Bs + row * BK + slot * 8);
      }
#pragma unroll
      for (int mi = 0; mi < 4; ++mi)
#pragma unroll
        for (int nj = 0; nj < 4; ++nj)
          acc[mi][nj] = __builtin_amdgcn_mfma_f32_16x16x32_bf16(av[mi], bv[nj], acc[mi][nj], 0, 0, 0);
    }
  }

  if constexpr (MODE == 1) {
#pragma unroll
    for (int nj = 0; nj < 4; ++nj) {
      float m = -INFINITY;
#pragma unroll
      for (int mi = 0; mi < 4; ++mi)
#pragma unroll
        for (int r = 0; r < 4; ++r) m = fmaxf(m, acc[mi][nj][r]);
      m = fmaxf(m, __shfl_xor(m, 16));
      m = fmaxf(m, __shfl_xor(m, 32));
      if (lane < 16) smax[wm][wn * 64 + nj * 16 + lr] = m;
    }
    __syncthreads();
    if (tid < 128) {
      float m = fmaxf(smax[0][tid], smax[1][tid]);
      pmaxOut[(size_t)blockIdx.y * C3 + n0 + tid] = m + bias[n0 + tid];
    }
  } else {
#pragma unroll
    for (int mi = 0; mi < 4; ++mi)
#pragma unroll
      for (int nj = 0; nj < 4; ++nj)
#pragma unroll
        for (int r = 0; r < 4; ++r) {
          int lrow = wm * 64 + mi * 16 + g * 4 + r;
          int col = n0 + wn * 64 + nj * 16 + lr;
          float v = acc[mi][nj][r] + bias[col];
          if (relu) v = fmaxf(v, 0.f);
          ushortT b = f2b(v);
          if constexpr (MODE == 0) {
            Cb[(size_t)(m0 + lrow) * ldc + col] = b;
          } else if constexpr (MODE == 2) {
            if (lrow < nr) Cb[(size_t)(bucket0 + lrow) * ldc + col] = b;
          } else {  // MODE 3
            if (lrow < nr) Cb[(size_t)pts[lrow] * ldc + 8 + col] = b;
          }
        }
  }
}

// ---------------------------------------------------------------------------
// latent = max over 8 m-tiles per batch
// ---------------------------------------------------------------------------
__global__ __launch_bounds__(256) void k_latmax(
    const float* __restrict__ pmax, float* __restrict__ lat, float* __restrict__ outLat) {
  int id = blockIdx.x * 256 + threadIdx.x;
  int b = id >> 10, o = id & 1023;
  float m = -INFINITY;
  for (int t = 0; t < 8; ++t)
    m = fmaxf(m, pmax[(size_t)((b << 3) + t) * C3 + o]);
  lat[id] = m;
  outLat[id] = m;
}

// ---------------------------------------------------------------------------
// Decoder (fp32, HBM-bound): K-split partial GEMM + reduce
// ---------------------------------------------------------------------------
__global__ __launch_bounds__(256) void k_gemm_part(
    const float* __restrict__ A, const float* __restrict__ W,
    float* __restrict__ part, int K, int Ncol, int chunkLog) {
  __shared__ float a[8][256];
  int chunk = 1 << chunkLog;
  int i0 = blockIdx.y << chunkLog;
  int j = blockIdx.x * 256 + threadIdx.x;
  for (int k = threadIdx.x; k < 8 * chunk; k += 256) {
    int r = k >> chunkLog, i = k & (chunk - 1);
    a[r][i] = A[(size_t)r * K + i0 + i];
  }
  __syncthreads();
  float acc[8];
#pragma unroll
  for (int r = 0; r < 8; ++r) acc[r] = 0.f;
  const float* wp = W + (size_t)i0 * Ncol + j;
  for (int i4 = 0; i4 < (chunk >> 2); ++i4) {
    float w0 = wp[(size_t)(4 * i4 + 0) * Ncol];
    float w1 = wp[(size_t)(4 * i4 + 1) * Ncol];
    float w2 = wp[(size_t)(4 * i4 + 2) * Ncol];
    float w3 = wp[(size_t)(4 * i4 + 3) * Ncol];
#pragma unroll
    for (int r = 0; r < 8; ++r) {
      float4 av = ((const float4*)a[r])[i4];
      acc[r] += av.x * w0 + av.y * w1 + av.z * w2 + av.w * w3;
    }
  }
#pragma unroll
  for (int r = 0; r < 8; ++r)
    part[((size_t)(blockIdx.y * 8 + r)) * Ncol + j] = acc[r];
}

__global__ __launch_bounds__(256) void k_reduce(
    const float* __restrict__ part, const float* __restrict__ bias,
    float* __restrict__ out, int ncolLog, int KC, int doRelu) {
  int o = blockIdx.x * 256 + threadIdx.x;
  int j = o & ((1 << ncolLog) - 1);
  float s = bias[j];
  for (int kc = 0; kc < KC; ++kc)
    s += part[((size_t)kc << (ncolLog + 3)) + o];
  if (doRelu) s = fmaxf(s, 0.f);
  out[o] = s;
}

// ---------------------------------------------------------------------------
extern "C" void kernel_launch(void* const* d_in, const int* in_sizes, int n_in,
                              void* d_out, int out_size, void* d_ws, size_t ws_size,
                              hipStream_t stream) {
  const float* x    = (const float*)d_in[0];
  const int*   cats = (const int*)d_in[1];
  const float* W1   = (const float*)d_in[2];
  const float* b1   = (const float*)d_in[3];
  const float* W2   = (const float*)d_in[4];
  const float* b2   = (const float*)d_in[5];
  const float* Wc1  = (const float*)d_in[6];
  const float* bc1  = (const float*)d_in[7];
  const float* Wc2  = (const float*)d_in[8];
  const float* bc2  = (const float*)d_in[9];
  const float* Wc3  = (const float*)d_in[10];
  const float* bc3  = (const float*)d_in[11];
  const float* Wd1  = (const float*)d_in[12];
  const float* bd1  = (const float*)d_in[13];
  const float* Wd2  = (const float*)d_in[14];
  const float* bd2  = (const float*)d_in[15];
  const float* Wd3  = (const float*)d_in[16];
  const float* bd3  = (const float*)d_in[17];
  float* out = (float*)d_out;                 // [8*1024*8] out  then [8*1024] latent

  char* wsb = (char*)d_ws;
  ushortT* xTb  = (ushortT*)(wsb + OB_XTB);
  ushortT* hB   = (ushortT*)(wsb + OB_HB);
  ushortT* h2   = (ushortT*)(wsb + OB_H2);
  ushortT* xi   = (ushortT*)(wsb + OB_XI);
  ushortT* h1   = (ushortT*)(wsb + OB_H1);
  ushortT* Wt1b = (ushortT*)(wsb + OB_WT1);
  ushortT* Wt2b = (ushortT*)(wsb + OB_WT2);
  ushortT* Wt3b = (ushortT*)(wsb + OB_WT3);
  ushortT* W1tb = (ushortT*)(wsb + OB_W1T);
  ushortT* W2tb = (ushortT*)(wsb + OB_W2T);
  float* pmax   = (float*)(wsb + OB_PMAX);
  float* lat    = (float*)(wsb + OB_LAT);
  float* d1w    = (float*)(wsb + OB_D1);
  float* d2w    = (float*)(wsb + OB_D2);
  float* dpart  = (float*)(wsb + OB_DPART);
  int*   idx    = (int*)(wsb + OB_IDX);
  int*   offs   = (int*)(wsb + OB_OFFS);

  // ---- prep: bf16 conversions / transposes ----
  k_prep_x<<<dim3(32, 9, BB), 256, 0, stream>>>(x, xTb, xi);
  k_zero_xi<<<(NPTS * 56 + 255) / 256, 256, 0, stream>>>(xi);
  k_cvt_pad<<<(256 * K1P + 255) / 256, 256, 0, stream>>>(Wc1, Wt1b, 136, K1P, 256 * K1P);
  k_cvt_pad<<<(512 * 256 + 255) / 256, 256, 0, stream>>>(Wc2, Wt2b, 256, 256, 512 * 256);
  k_cvt_pad<<<(1024 * 512 + 255) / 256, 256, 0, stream>>>(Wc3, Wt3b, 512, 512, 1024 * 512);
  k_transpose_wb<<<dim3(8, 8, NE), 256, 0, stream>>>(W1, W1tb, 256, 256, 65536, 65536);
  k_transpose_wb<<<dim3(4, 8, NE), 256, 0, stream>>>(W2, W2tb, 256, 128, 32768, 32768);

  // ---- routing: bucket + 2 expert-batched MFMA GEMMs ----
  k_bucket<<<1, 1024, 0, stream>>>(cats, idx, offs);
  k_gemm<2><<<dim3(2, NE, 8), 256, 0, stream>>>(xTb, XCH, W1tb, 256, b1, hB, 256,
                                                nullptr, idx, offs, 256, 1);
  k_gemm<3><<<dim3(1, NE, 8), 256, 0, stream>>>(hB, 256, W2tb, 256, b2, xi, K1P,
                                                nullptr, idx, offs, 256, 0);

  // ---- conv stack (MFMA) + fused col-max ----
  k_gemm<0><<<dim3(2, 64), 256, 0, stream>>>(xi, K1P, Wt1b, K1P, bc1, h1, 256,
                                             nullptr, nullptr, nullptr, K1P, 1);
  k_gemm<0><<<dim3(4, 64), 256, 0, stream>>>(h1, 256, Wt2b, 256, bc2, h2, 512,
                                             nullptr, nullptr, nullptr, 256, 1);
  k_gemm<1><<<dim3(8, 64), 256, 0, stream>>>(h2, 512, Wt3b, 512, bc3, nullptr, 0,
                                             pmax, nullptr, nullptr, 512, 0);
  k_latmax<<<32, 256, 0, stream>>>(pmax, lat, out + 65536);

  // ---- decoder (fp32) ----
  k_gemm_part<<<dim3(4, 32), 256, 0, stream>>>(lat, Wd1, dpart, 1024, 1024, 5);
  k_reduce<<<32, 256, 0, stream>>>(dpart, bd1, d1w, 10, 32, 1);
  k_gemm_part<<<dim3(8, 16), 256, 0, stream>>>(d1w, Wd2, dpart, 1024, 2048, 6);
  k_reduce<<<64, 256, 0, stream>>>(dpart, bd2, d2w, 11, 16, 1);
  k_gemm_part<<<dim3(32, 8), 256, 0, stream>>>(d2w, Wd3, dpart, 2048, 8192, 8);
  k_reduce<<<256, 256, 0, stream>>>(dpart, bd3, out, 13, 8, 0);
  (void)in_sizes; (void)n_in; (void)out_size; (void)ws_size;
}

// Round 3
// 306.628 us; speedup vs baseline: 2.4476x; 1.0162x over previous
//
#include <hip/hip_runtime.h>
#include <math.h>

// ---- problem constants ----
#define BB 8
#define NN 1024
#define HEADC 8
#define SS 256
#define SCO 128
#define NE 16
#define C1 256
#define C2 512
#define C3 1024
#define NPTS (BB*NN)      // 8192
#define XCH (HEADC+SS)    // 264
#define K1P 192           // conv L1 K padded (136 -> 192)
#define BK 64

typedef unsigned short ushortT;
typedef __attribute__((ext_vector_type(8))) short bf16x8;   // 8 bf16 = 4 VGPRs
typedef __attribute__((ext_vector_type(4))) float f32x4;

// ---- workspace layout (byte offsets, all 256-aligned) ----
// h2 [8192][512]bf16 aliases XTB+HB (both dead by conv L2)
#define OB_XTB   0ull          // ushort [8192][264]
#define OB_HB    4325376ull    // ushort [8192][256]  (bucket-ordered hidden)
#define OB_H2    0ull          // ushort [8192][512]
#define OB_XI    8519680ull    // ushort [8192][192]  (head 8 | routed 128 | pad 56)
#define OB_H1    11665408ull   // ushort [8192][256]
#define OB_WT1   15859712ull   // ushort [256][192]
#define OB_WT2   15958016ull   // ushort [512][256]
#define OB_WT3   16220160ull   // ushort [1024][512]
#define OB_W1T   17268736ull   // ushort [16][256][256]
#define OB_W2T   19365888ull   // ushort [16][128][256]
#define OB_PMAX  20414464ull   // float [64][1024]
#define OB_LAT   20676608ull   // float [8][1024]
#define OB_D1    20709376ull   // float [8][1024]
#define OB_D2    20742144ull   // float [8][2048]
#define OB_DPART 20807680ull   // float, up to 4 MB (L3: 16 chunks x 8 x 8192)
#define OB_IDX   25001984ull   // int [8192]
#define OB_OFFS  25034752ull   // int [17]

__device__ __forceinline__ ushortT f2b(float f) {
  unsigned u = __float_as_uint(f);
  return (ushortT)((u + 0x7FFFu + ((u >> 16) & 1u)) >> 16);
}

// ---------------------------------------------------------------------------
// x [B][264][1024] f32  ->  xTb [B*N][264] bf16 ; head cols into xi
// ---------------------------------------------------------------------------
__global__ __launch_bounds__(256) void k_prep_x(
    const float* __restrict__ x, ushortT* __restrict__ xTb, ushortT* __restrict__ xi) {
  __shared__ float t[32][33];
  int b = blockIdx.z;
  int n0 = blockIdx.x * 32, c0 = blockIdx.y * 32;
  int tx = threadIdx.x & 31, ty = threadIdx.x >> 5;
  const float* s = x + (size_t)b * XCH * NN;
  for (int yy = ty; yy < 32; yy += 8) {
    int c = c0 + yy;
    if (c < XCH) t[yy][tx] = s[(size_t)c * NN + n0 + tx];
  }
  __syncthreads();
  for (int yy = ty; yy < 32; yy += 8) {
    int n = n0 + yy, c = c0 + tx;
    if (c < XCH) {
      ushortT v = f2b(t[tx][yy]);
      xTb[(size_t)(b * NN + n) * XCH + c] = v;
      if (c < HEADC) xi[(size_t)(b * NN + n) * K1P + c] = v;
    }
  }
}

// ---------------------------------------------------------------------------
// All conv-weight conversions in one kernel.
// Wc1 [256][136] -> Wt1b [256][192] (pad 0); Wc2 -> Wt2b; Wc3 -> Wt3b (straight)
// ---------------------------------------------------------------------------
#define CW_S1 (256*192)
#define CW_S2 (512*256)
#define CW_S3 (1024*512)
__global__ __launch_bounds__(256) void k_cvt_weights(
    const float* __restrict__ Wc1, const float* __restrict__ Wc2,
    const float* __restrict__ Wc3, ushortT* __restrict__ w1,
    ushortT* __restrict__ w2, ushortT* __restrict__ w3) {
  int i = blockIdx.x * 256 + threadIdx.x;
  if (i < CW_S1) {
    int r = i / K1P, c = i - r * K1P;
    w1[i] = (c < 136) ? f2b(Wc1[(size_t)r * 136 + c]) : (ushortT)0;
  } else if (i < CW_S1 + CW_S2) {
    int k = i - CW_S1;
    w2[k] = f2b(Wc2[k]);
  } else if (i < CW_S1 + CW_S2 + CW_S3) {
    int k = i - CW_S1 - CW_S2;
    w3[k] = f2b(Wc3[k]);
  }
}

// ---------------------------------------------------------------------------
// Merged expert-weight transposes: z<16 -> W1 ([256][256]), z>=16 -> W2 ([256][128])
// f32 [in][out] -> bf16 [out][in]
// ---------------------------------------------------------------------------
__global__ __launch_bounds__(256) void k_transpose_w12(
    const float* __restrict__ W1, const float* __restrict__ W2,
    ushortT* __restrict__ W1tb, ushortT* __restrict__ W2tb) {
  __shared__ float t[32][33];
  int z = blockIdx.z;
  const float* s;
  ushortT* d;
  int C;
  if (z < 16) { s = W1 + (size_t)z * 65536; d = W1tb + (size_t)z * 65536; C = 256; }
  else {
    if (blockIdx.x >= 4) return;
    s = W2 + (size_t)(z - 16) * 32768; d = W2tb + (size_t)(z - 16) * 32768; C = 128;
  }
  const int R = 256;
  int r0 = blockIdx.y * 32, c0 = blockIdx.x * 32;
  int tx = threadIdx.x & 31, ty = threadIdx.x >> 5;
  for (int yy = ty; yy < 32; yy += 8) {
    int r = r0 + yy, c = c0 + tx;
    if (c < C) t[yy][tx] = s[(size_t)r * C + c];
  }
  __syncthreads();
  for (int yy = ty; yy < 32; yy += 8) {
    int c = c0 + yy, r = r0 + tx;
    if (c < C) d[(size_t)c * R + r] = f2b(t[tx][yy]);
  }
}

// ---------------------------------------------------------------------------
// Bucket points by category (single block)
// ---------------------------------------------------------------------------
__global__ __launch_bounds__(1024) void k_bucket(
    const int* __restrict__ cats, int* __restrict__ idx, int* __restrict__ offs) {
  __shared__ int cnt[NE];
  __shared__ int base[NE + 1];
  __shared__ int cur[NE];
  int tid = threadIdx.x;
  if (tid < NE) cnt[tid] = 0;
  __syncthreads();
  for (int p = tid; p < NPTS; p += 1024) atomicAdd(&cnt[cats[p]], 1);
  __syncthreads();
  if (tid == 0) {
    int s = 0;
    for (int e = 0; e < NE; ++e) { base[e] = s; cur[e] = s; s += cnt[e]; }
    base[NE] = s;
  }
  __syncthreads();
  for (int p = tid; p < NPTS; p += 1024) {
    int pos = atomicAdd(&cur[cats[p]], 1);
    idx[pos] = p;
  }
  if (tid <= NE) offs[tid] = base[tid];
}

// ---------------------------------------------------------------------------
// Generic bf16 MFMA GEMM, 128x128 tile, 4 waves (2x2 of 64x64), BK=64.
// XOR swizzle: 16B chunk slot ^= (row&7)  -> conflict-free ds_write/ds_read_b128.
// MODE 0: C_bf16 = maybe_relu(acc + bias)      (conv L1/L2)
// MODE 1: pmax[by][col] = colmax(acc) + bias   (conv L3)
// MODE 2: gather A via idx (xTb +8); C bucket-linear   (route L1)
// MODE 3: A bucket-linear; scatter C via idx (+8)      (route L2)
// ---------------------------------------------------------------------------
template<int MODE>
__global__ __launch_bounds__(256) void k_gemm(
    const ushortT* __restrict__ A, int lda,
    const ushortT* __restrict__ Bt, int ldb,
    const float* __restrict__ bias,
    ushortT* __restrict__ Cb, int ldc,
    float* __restrict__ pmaxOut,
    const int* __restrict__ idx, const int* __restrict__ offsp,
    int K, int relu) {
  __shared__ ushortT As[128 * BK];
  __shared__ ushortT Bs[128 * BK];
  __shared__ int pts[128];
  __shared__ float smax[2][128];
  int tid = threadIdx.x;
  int wave = tid >> 6, lane = tid & 63;
  int wm = wave >> 1, wn = wave & 1;
  int g = lane >> 4, lr = lane & 15;
  int n0 = blockIdx.x * 128;
  int m0 = 0, nr = 128, bucket0 = 0;

  if constexpr (MODE == 2 || MODE == 3) {
    int e = blockIdx.y, t = blockIdx.z;
    int s0 = offsp[e];
    int cnt = offsp[e + 1] - s0;
    int p0 = t * 128;
    if (p0 >= cnt) return;
    nr = min(128, cnt - p0);
    bucket0 = s0 + p0;
    Bt += (size_t)e * ((MODE == 2) ? 256 * 256 : 128 * 256);
    bias += e * ((MODE == 2) ? 256 : 128);
    if (tid < 128) pts[tid] = (tid < nr) ? idx[bucket0 + tid] : 0;
  } else {
    m0 = blockIdx.y * 128;
  }

  f32x4 acc[4][4];
#pragma unroll
  for (int mi = 0; mi < 4; ++mi)
#pragma unroll
    for (int nj = 0; nj < 4; ++nj) acc[mi][nj] = (f32x4)(0.f);

  int nkt = K / BK;
  for (int kt = 0; kt < nkt; ++kt) {
    int k0 = kt * BK;
    __syncthreads();   // LDS reuse guard (covers pts staging on kt==0)
#pragma unroll
    for (int i = 0; i < 4; ++i) {
      int c = tid + i * 256;
      int row = c >> 3, slot = c & 7;
      int ss = slot ^ (row & 7);
      uint4 v;
      if constexpr (MODE == 2) {
        if (row < nr) v = *(const uint4*)(A + (size_t)pts[row] * lda + 8 + k0 + slot * 8);
        else { v.x = v.y = v.z = v.w = 0u; }
      } else if constexpr (MODE == 3) {
        if (row < nr) v = *(const uint4*)(A + (size_t)(bucket0 + row) * lda + k0 + slot * 8);
        else { v.x = v.y = v.z = v.w = 0u; }
      } else {
        v = *(const uint4*)(A + (size_t)(m0 + row) * lda + k0 + slot * 8);
      }
      *(uint4*)(As + row * BK + ss * 8) = v;
      uint4 w = *(const uint4*)(Bt + (size_t)(n0 + row) * ldb + k0 + slot * 8);
      *(uint4*)(Bs + row * BK + ss * 8) = w;
    }
    __syncthreads();
#pragma unroll
    for (int kk = 0; kk < 2; ++kk) {
      bf16x8 av[4], bv[4];
#pragma unroll
      for (int mi = 0; mi < 4; ++mi) {
        int row = wm * 64 + mi * 16 + lr;
        int slot = (kk * 4 + g) ^ (row & 7);
        av[mi] = *(const bf16x8*)(As + row * BK + slot * 8);
      }
#pragma unroll
      for (int nj = 0; nj < 4; ++nj) {
        int row = wn * 64 + nj * 16 + lr;
        int slot = (kk * 4 + g) ^ (row & 7);
        bv[nj] = *(const bf16x8*)(Bs + row * BK + slot * 8);
      }
#pragma unroll
      for (int mi = 0; mi < 4; ++mi)
#pragma unroll
        for (int nj = 0; nj < 4; ++nj)
          acc[mi][nj] = __builtin_amdgcn_mfma_f32_16x16x32_bf16(av[mi], bv[nj], acc[mi][nj], 0, 0, 0);
    }
  }

  if constexpr (MODE == 1) {
#pragma unroll
    for (int nj = 0; nj < 4; ++nj) {
      float m = -INFINITY;
#pragma unroll
      for (int mi = 0; mi < 4; ++mi)
#pragma unroll
        for (int r = 0; r < 4; ++r) m = fmaxf(m, acc[mi][nj][r]);
      m = fmaxf(m, __shfl_xor(m, 16));
      m = fmaxf(m, __shfl_xor(m, 32));
      if (lane < 16) smax[wm][wn * 64 + nj * 16 + lr] = m;
    }
    __syncthreads();
    if (tid < 128) {
      float m = fmaxf(smax[0][tid], smax[1][tid]);
      pmaxOut[(size_t)blockIdx.y * C3 + n0 + tid] = m + bias[n0 + tid];
    }
  } else {
#pragma unroll
    for (int mi = 0; mi < 4; ++mi)
#pragma unroll
      for (int nj = 0; nj < 4; ++nj)
#pragma unroll
        for (int r = 0; r < 4; ++r) {
          int lrow = wm * 64 + mi * 16 + g * 4 + r;
          int col = n0 + wn * 64 + nj * 16 + lr;
          float v = acc[mi][nj][r] + bias[col];
          if (relu) v = fmaxf(v, 0.f);
          ushortT b = f2b(v);
          if constexpr (MODE == 0) {
            Cb[(size_t)(m0 + lrow) * ldc + col] = b;
          } else if constexpr (MODE == 2) {
            if (lrow < nr) Cb[(size_t)(bucket0 + lrow) * ldc + col] = b;
          } else {  // MODE 3
            if (lrow < nr) Cb[(size_t)pts[lrow] * ldc + 8 + col] = b;
          }
        }
  }
}

// ---------------------------------------------------------------------------
// latent = max over 8 m-tiles per batch (f32x4)
// ---------------------------------------------------------------------------
__global__ __launch_bounds__(256) void k_latmax(
    const float* __restrict__ pmax, float* __restrict__ lat, float* __restrict__ outLat) {
  int id4 = blockIdx.x * 256 + threadIdx.x;      // 0..2047
  int b = id4 >> 8, o4 = id4 & 255;
  f32x4 m = (f32x4)(-INFINITY);
  for (int t = 0; t < 8; ++t) {
    f32x4 v = *(const f32x4*)(pmax + (size_t)((b << 3) + t) * C3 + o4 * 4);
#pragma unroll
    for (int r = 0; r < 4; ++r) m[r] = fmaxf(m[r], v[r]);
  }
  *(f32x4*)(lat + (size_t)id4 * 4) = m;
  *(f32x4*)(outLat + (size_t)id4 * 4) = m;
}

// ---------------------------------------------------------------------------
// Decoder partial GEMM, f32x4: A[8][K] @ W[K][N], k-split.
// grid (N / (blockDim*4), K >> chunkLog). Each thread: 4 consecutive cols.
// ---------------------------------------------------------------------------
__global__ __launch_bounds__(256) void k_dec_part(
    const float* __restrict__ A, const float* __restrict__ W,
    float* __restrict__ part, int K, int N, int chunkLog) {
  __shared__ float a[8 * 128];
  int chunk = 1 << chunkLog;
  int i0 = blockIdx.y << chunkLog;
  int tid = threadIdx.x;
  for (int idx = tid; idx < (8 << chunkLog); idx += blockDim.x) {
    int r = idx >> chunkLog, i = idx & (chunk - 1);
    a[idx] = A[(size_t)r * K + i0 + i];
  }
  __syncthreads();
  int col = (blockIdx.x * blockDim.x + tid) * 4;
  f32x4 acc[8];
#pragma unroll
  for (int r = 0; r < 8; ++r) acc[r] = (f32x4)(0.f);
  const float* wp = W + (size_t)i0 * N + col;
#pragma unroll 2
  for (int k = 0; k < chunk; k += 4) {
    f32x4 w0 = *(const f32x4*)(wp + (size_t)(k + 0) * N);
    f32x4 w1 = *(const f32x4*)(wp + (size_t)(k + 1) * N);
    f32x4 w2 = *(const f32x4*)(wp + (size_t)(k + 2) * N);
    f32x4 w3 = *(const f32x4*)(wp + (size_t)(k + 3) * N);
#pragma unroll
    for (int r = 0; r < 8; ++r) {
      const float* ar = &a[(r << chunkLog) + k];
      acc[r] += ar[0] * w0 + ar[1] * w1 + ar[2] * w2 + ar[3] * w3;
    }
  }
  float* pp = part + (size_t)(blockIdx.y * 8) * N + col;
#pragma unroll
  for (int r = 0; r < 8; ++r) *(f32x4*)(pp + (size_t)r * N) = acc[r];
}

// reduce partials (f32x4): out[8][N] = relu?(bias + sum_kc part[kc][8][N])
__global__ __launch_bounds__(256) void k_reduce4(
    const float* __restrict__ part, const float* __restrict__ bias,
    float* __restrict__ out, int N, int KC, int doRelu) {
  int o4 = blockIdx.x * 256 + threadIdx.x;       // index into [8][N/4]
  int col4 = o4 & ((N >> 2) - 1);
  f32x4 s = ((const f32x4*)bias)[col4];
  const f32x4* p4 = (const f32x4*)part;
  for (int kc = 0; kc < KC; ++kc)
    s += p4[(size_t)kc * 2 * N + o4];
  if (doRelu) {
#pragma unroll
    for (int r = 0; r < 4; ++r) s[r] = fmaxf(s[r], 0.f);
  }
  ((f32x4*)out)[o4] = s;
}

// ---------------------------------------------------------------------------
extern "C" void kernel_launch(void* const* d_in, const int* in_sizes, int n_in,
                              void* d_out, int out_size, void* d_ws, size_t ws_size,
                              hipStream_t stream) {
  const float* x    = (const float*)d_in[0];
  const int*   cats = (const int*)d_in[1];
  const float* W1   = (const float*)d_in[2];
  const float* b1   = (const float*)d_in[3];
  const float* W2   = (const float*)d_in[4];
  const float* b2   = (const float*)d_in[5];
  const float* Wc1  = (const float*)d_in[6];
  const float* bc1  = (const float*)d_in[7];
  const float* Wc2  = (const float*)d_in[8];
  const float* bc2  = (const float*)d_in[9];
  const float* Wc3  = (const float*)d_in[10];
  const float* bc3  = (const float*)d_in[11];
  const float* Wd1  = (const float*)d_in[12];
  const float* bd1  = (const float*)d_in[13];
  const float* Wd2  = (const float*)d_in[14];
  const float* bd2  = (const float*)d_in[15];
  const float* Wd3  = (const float*)d_in[16];
  const float* bd3  = (const float*)d_in[17];
  float* out = (float*)d_out;                 // [8*1024*8] out  then [8*1024] latent

  char* wsb = (char*)d_ws;
  ushortT* xTb  = (ushortT*)(wsb + OB_XTB);
  ushortT* hB   = (ushortT*)(wsb + OB_HB);
  ushortT* h2   = (ushortT*)(wsb + OB_H2);
  ushortT* xi   = (ushortT*)(wsb + OB_XI);
  ushortT* h1   = (ushortT*)(wsb + OB_H1);
  ushortT* Wt1b = (ushortT*)(wsb + OB_WT1);
  ushortT* Wt2b = (ushortT*)(wsb + OB_WT2);
  ushortT* Wt3b = (ushortT*)(wsb + OB_WT3);
  ushortT* W1tb = (ushortT*)(wsb + OB_W1T);
  ushortT* W2tb = (ushortT*)(wsb + OB_W2T);
  float* pmax   = (float*)(wsb + OB_PMAX);
  float* lat    = (float*)(wsb + OB_LAT);
  float* d1w    = (float*)(wsb + OB_D1);
  float* d2w    = (float*)(wsb + OB_D2);
  float* dpart  = (float*)(wsb + OB_DPART);
  int*   idx    = (int*)(wsb + OB_IDX);
  int*   offs   = (int*)(wsb + OB_OFFS);

  // ---- prep: bf16 conversions / transposes (xi pad cols stay garbage:
  //      multiplied by zero weight pads, contributes exactly 0) ----
  k_prep_x<<<dim3(32, 9, BB), 256, 0, stream>>>(x, xTb, xi);
  k_cvt_weights<<<(CW_S1 + CW_S2 + CW_S3 + 255) / 256, 256, 0, stream>>>(
      Wc1, Wc2, Wc3, Wt1b, Wt2b, Wt3b);
  k_transpose_w12<<<dim3(8, 8, 32), 256, 0, stream>>>(W1, W2, W1tb, W2tb);

  // ---- routing: bucket + 2 expert-batched MFMA GEMMs ----
  k_bucket<<<1, 1024, 0, stream>>>(cats, idx, offs);
  k_gemm<2><<<dim3(2, NE, 8), 256, 0, stream>>>(xTb, XCH, W1tb, 256, b1, hB, 256,
                                                nullptr, idx, offs, 256, 1);
  k_gemm<3><<<dim3(1, NE, 8), 256, 0, stream>>>(hB, 256, W2tb, 256, b2, xi, K1P,
                                                nullptr, idx, offs, 256, 0);

  // ---- conv stack (MFMA) + fused col-max ----
  k_gemm<0><<<dim3(2, 64), 256, 0, stream>>>(xi, K1P, Wt1b, K1P, bc1, h1, 256,
                                             nullptr, nullptr, nullptr, K1P, 1);
  k_gemm<0><<<dim3(4, 64), 256, 0, stream>>>(h1, 256, Wt2b, 256, bc2, h2, 512,
                                             nullptr, nullptr, nullptr, 256, 1);
  k_gemm<1><<<dim3(8, 64), 256, 0, stream>>>(h2, 512, Wt3b, 512, bc3, nullptr, 0,
                                             pmax, nullptr, nullptr, 512, 0);
  k_latmax<<<8, 256, 0, stream>>>(pmax, lat, out + 65536);

  // ---- decoder (fp32, f32x4 wide loads, k-split) ----
  // L1: 1024x1024, 64 thr -> 256 cols/block, chunk 32 -> grid (4,32)=128
  k_dec_part<<<dim3(4, 32), 64, 0, stream>>>(lat, Wd1, dpart, 1024, 1024, 5);
  k_reduce4<<<8, 256, 0, stream>>>(dpart, bd1, d1w, 1024, 32, 1);
  // L2: 1024x2048, 64 thr -> 256 cols/block, chunk 32 -> grid (8,32)=256
  k_dec_part<<<dim3(8, 32), 64, 0, stream>>>(d1w, Wd2, dpart, 1024, 2048, 5);
  k_reduce4<<<16, 256, 0, stream>>>(dpart, bd2, d2w, 2048, 32, 1);
  // L3: 2048x8192, 256 thr -> 1024 cols/block, chunk 128 -> grid (8,16)=128
  k_dec_part<<<dim3(8, 16), 256, 0, stream>>>(d2w, Wd3, dpart, 2048, 8192, 7);
  k_reduce4<<<64, 256, 0, stream>>>(dpart, bd3, out, 8192, 16, 0);
  (void)in_sizes; (void)n_in; (void)out_size; (void)ws_size;
}